// Round 5
// baseline (694.629 us; speedup 1.0000x reference)
//
#include <hip/hip_runtime.h>
#include <cstdint>

#define EMB 1024
#define HID 2048
#define BATCH 4
#define SEQ 2048
#define MROWS (BATCH * SEQ) /* 8192 */
#define N1 (3 * HID)        /* 6144 */
#define K1 EMB              /* 1024 */
#define N2 EMB              /* 1024 */
#define K2 HID              /* 2048 */

#define NX (MROWS * EMB)  /* 8388608 */
#define NW1 (N1 * K1)     /* 6291456 */
#define NW2 (N2 * K2)     /* 2097152 */

typedef unsigned short ushort_t;
typedef __bf16 bf16x8 __attribute__((ext_vector_type(8)));
typedef float f32x4 __attribute__((ext_vector_type(4)));
typedef ushort_t us4 __attribute__((ext_vector_type(4)));

__device__ __forceinline__ ushort_t f2bf(float f) {
    uint32_t u = __builtin_bit_cast(uint32_t, f);
    u += 0x7fffu + ((u >> 16) & 1u);  // round-to-nearest-even
    return (ushort_t)(u >> 16);
}
__device__ __forceinline__ float bf2f(ushort_t h) {
    uint32_t u = ((uint32_t)h) << 16;
    return __builtin_bit_cast(float, u);
}
__device__ __forceinline__ float sigm(float x) {
    return 1.f / (1.f + __expf(-x));
}
__device__ __forceinline__ uint32_t f2u(float f) { return __builtin_bit_cast(uint32_t, f); }
__device__ __forceinline__ float u2f(uint32_t u) { return __builtin_bit_cast(float, u); }

// async global->LDS, 16B per lane; LDS dest is wave-uniform base + lane*16
__device__ __forceinline__ void gload_lds16(const ushort_t* g, const ushort_t* l) {
    __builtin_amdgcn_global_load_lds(
        (const __attribute__((address_space(1))) void*)(uintptr_t)(g),
        (__attribute__((address_space(3))) void*)(uint32_t)(uintptr_t)(l),
        16, 0, 0);
}

// ---------------------------------------------------------------------------
// fp32 -> bf16 pre-convert of x, w1, w2
// ---------------------------------------------------------------------------
__global__ __launch_bounds__(256) void cvt_kernel(
    const float* __restrict__ x, const float* __restrict__ w1,
    const float* __restrict__ w2, ushort_t* __restrict__ xb,
    ushort_t* __restrict__ w1b, ushort_t* __restrict__ w2b) {
    const int i = (blockIdx.x * 256 + threadIdx.x) * 4;
    const float* s;
    ushort_t* d;
    if (i < NX) {
        s = x + i; d = xb + i;
    } else if (i < NX + NW1) {
        s = w1 + (i - NX); d = w1b + (i - NX);
    } else {
        s = w2 + (i - NX - NW1); d = w2b + (i - NX - NW1);
    }
    const float4 v = *(const float4*)s;
    us4 o;
    o.x = f2bf(v.x); o.y = f2bf(v.y); o.z = f2bf(v.z); o.w = f2bf(v.w);
    *(us4*)d = o;
}

// ---------------------------------------------------------------------------
// C = A[M,K] * B[N,K]^T  (bf16 in, fp32 acc)
// OMODE 0: C row-major fp32 [M][N].
// OMODE 1: C transposed bf16 [N][M], written via padded-LDS transpose so
//   global stores are 256-B contiguous per wave (fixes R4's 1.6x WRITE_SIZE).
// K-loop identical to R2-R4 (bank-conflict-free swizzle, verified).
// ---------------------------------------------------------------------------
template <int OMODE>
__global__ __launch_bounds__(256) void gemm_bt(
    const ushort_t* __restrict__ A, const ushort_t* __restrict__ B,
    void* __restrict__ Cv, int M, int N, int K) {
    __shared__ ushort_t sA[128 * 32];
    __shared__ ushort_t sB[128 * 32];

    const int tid  = threadIdx.x;
    const int lane = tid & 63;
    const int wave = tid >> 6;
    const int quad = lane >> 4;
    const int l16  = lane & 15;
    const long tm0 = (long)blockIdx.y * 128;
    const long tn0 = (long)blockIdx.x * 128;
    const int wm = (wave & 1) * 64;
    const int wn = (wave >> 1) * 64;

    f32x4 acc[4][4] = {};

    const int ar0 = tid >> 2;
    const int ar1 = (tid + 256) >> 2;
    const int kq  = (tid & 3) ^ ((ar0 >> 1) & 3);
    const int ac  = kq * 8;
    const ushort_t* gA = A + (size_t)tm0 * K;
    const ushort_t* gB = B + (size_t)tn0 * K;
    ushort_t* lb0 = &sA[0] + wave * 512;
    ushort_t* lb1 = &sA[0] + 2048 + wave * 512;
    ushort_t* lb2 = &sB[0] + wave * 512;
    ushort_t* lb3 = &sB[0] + 2048 + wave * 512;

    const int rsw = (l16 >> 1) & 3;
    const int aoff = (quad ^ rsw) * 8 + l16 * 32;

    for (int k0 = 0; k0 < K; k0 += 32) {
        __syncthreads();
        gload_lds16(gA + (size_t)ar0 * K + k0 + ac, lb0);
        gload_lds16(gA + (size_t)ar1 * K + k0 + ac, lb1);
        gload_lds16(gB + (size_t)ar0 * K + k0 + ac, lb2);
        gload_lds16(gB + (size_t)ar1 * K + k0 + ac, lb3);
        __syncthreads();

        bf16x8 af[4], bfr[4];
#pragma unroll
        for (int i = 0; i < 4; ++i)
            af[i] = *(const bf16x8*)&sA[(wm + i * 16) * 32 + aoff];
#pragma unroll
        for (int j = 0; j < 4; ++j)
            bfr[j] = *(const bf16x8*)&sB[(wn + j * 16) * 32 + aoff];
#pragma unroll
        for (int i = 0; i < 4; ++i)
#pragma unroll
            for (int j = 0; j < 4; ++j)
                acc[i][j] = __builtin_amdgcn_mfma_f32_16x16x32_bf16(
                    af[i], bfr[j], acc[i][j], 0, 0, 0);
    }

    // epilogue: C/D layout col=lane&15, row=quad*4+reg
    if constexpr (OMODE == 1) {
        // transposed bf16 [N][M] via LDS: 2 passes over col halves
        __shared__ ushort_t trans[64 * 132];  // [col_l][row], pad 132 (8B-aligned, 2-way read)
#pragma unroll
        for (int p = 0; p < 2; ++p) {
            __syncthreads();  // p=1: previous pass reads done
            if ((wave >> 1) == p) {  // the two waves whose wn == p*64
#pragma unroll
                for (int i = 0; i < 4; ++i)
#pragma unroll
                    for (int j = 0; j < 4; ++j) {
                        us4 o;
                        o.x = f2bf(acc[i][j][0]); o.y = f2bf(acc[i][j][1]);
                        o.z = f2bf(acc[i][j][2]); o.w = f2bf(acc[i][j][3]);
                        *(us4*)&trans[(j * 16 + l16) * 132 + wm + i * 16 + quad * 4] = o;
                    }
            }
            __syncthreads();
            // write 64 cols x 128 rows; per wave-iter: 64 lanes x 4 B = 256 B contiguous
#pragma unroll
            for (int it = 0; it < 16; ++it) {
                const int col_l = it * 4 + wave;
                const uint32_t v = *(const uint32_t*)&trans[col_l * 132 + lane * 2];
                *(uint32_t*)&((ushort_t*)Cv)[(size_t)(tn0 + p * 64 + col_l) * M + tm0 + lane * 2] = v;
            }
        }
    } else {
#pragma unroll
        for (int i = 0; i < 4; ++i) {
            const long row0 = tm0 + wm + i * 16 + quad * 4;
#pragma unroll
            for (int j = 0; j < 4; ++j) {
                const long col = tn0 + wn + j * 16 + l16;
#pragma unroll
                for (int r = 0; r < 4; ++r)
                    ((float*)Cv)[(size_t)(row0 + r) * N + col] = acc[i][j][r];
            }
        }
    }
}

// ---------------------------------------------------------------------------
// Single-pass scan with decoupled look-back over yT [6144 ch][8192 (b,t)] bf16.
// Grid 1024 = b(4) x cg(32, 64ch) x tb(8, 256t), tb in blockIdx LSBs so
// predecessors have lower blockIdx. Block 256 thr = tseg(4 waves) x ch_l(64):
// wave = one 64-t sub-segment for 64 channels -> u stores 128-B coalesced.
// __launch_bounds__(256,4) => VGPR<=128 => 4 blocks/CU => all 1024 resident
// (deadlock-free look-back). Flags memset-0 before launch; READY=1.
// ---------------------------------------------------------------------------
#define READY 1u

__global__ __launch_bounds__(256, 4) void scan_lookback(
    const ushort_t* __restrict__ yT, const float* __restrict__ cw,
    float* __restrict__ IncA, float* __restrict__ IncB,
    uint32_t* __restrict__ flags, ushort_t* __restrict__ u) {
    __shared__ float tAg[4][64], tBg[4][64], tEa[4][64], tEb[4][64], tPb[64];
    const int bi   = blockIdx.x;
    const int b    = bi >> 8;
    const int cg   = (bi >> 3) & 31;
    const int tb   = bi & 7;
    const int ch_l = threadIdx.x & 63;
    const int tseg = threadIdx.x >> 6;
    const int ch   = cg * 64 + ch_l;
    const int t0   = tb * 256 + tseg * 64;
    const size_t pos = (size_t)b * SEQ + t0;
    const ushort_t* zp = yT + (size_t)(2048 + ch) * MROWS + pos;
    const ushort_t* hp = yT + (size_t)(4096 + ch) * MROWS + pos;
    const ushort_t* op = yT + (size_t)ch * MROWS + pos;

    uint4 za[8], ha[8];
#pragma unroll
    for (int j = 0; j < 8; ++j) {
        za[j] = *(const uint4*)(zp + j * 8);
        ha[j] = *(const uint4*)(hp + j * 8);
    }
    float zw1 = 0.f, zw2 = 0.f, zw3 = 0.f;  // conv warm-up (t0-1, t0-2, t0-3)
    if (t0) {
        const uint2 w = *(const uint2*)(zp - 4);
        zw3 = bf2f((ushort_t)(w.x >> 16));
        zw2 = bf2f((ushort_t)(w.y & 0xffff));
        zw1 = bf2f((ushort_t)(w.y >> 16));
    }
    const float w0 = cw[ch * 4 + 0], w1 = cw[ch * 4 + 1];
    const float w2 = cw[ch * 4 + 2], w3 = cw[ch * 4 + 3];

    const ushort_t* zs = (const ushort_t*)za;
    const ushort_t* hs = (const ushort_t*)ha;

    // phase A: per-(ch, tseg) aggregate
    float z1 = zw1, z2 = zw2, z3 = zw3;
    float Aa = 1.f, Bv = 0.f;
#pragma unroll
    for (int t = 0; t < 64; ++t) {
        const float zr = bf2f(zs[t]);
        const float hr = bf2f(hs[t]);
        const float cv = w0 * z3 + w1 * z2 + w2 * z1 + w3 * zr;
        const float s  = sigm(cv);
        z3 = z2; z2 = z1; z1 = zr;
        const float a = 1.f - s;
        Aa *= a;
        Bv = a * Bv + s * hr;
    }
    tAg[tseg][ch_l] = Aa;
    tBg[tseg][ch_l] = Bv;
    __syncthreads();

    // phase B (tid<64): intra-block exclusive prefixes + look-back + publish
    if (threadIdx.x < 64) {
        const int c = threadIdx.x;
        float ea = 1.f, eb = 0.f;
#pragma unroll
        for (int ts = 0; ts < 4; ++ts) {
            tEa[ts][c] = ea;
            tEb[ts][c] = eb;
            const float a = tAg[ts][c], bb = tBg[ts][c];
            eb = a * eb + bb;
            ea = a * ea;
        }
        // (ea, eb) = block aggregate G
        float Pa = 1.f, Pb = 0.f;
        if (tb) {
            const int pred = bi - 1;
            while (__hip_atomic_load(&flags[pred], __ATOMIC_ACQUIRE,
                                     __HIP_MEMORY_SCOPE_AGENT) != READY)
                __builtin_amdgcn_s_sleep(8);
            Pa = u2f(__hip_atomic_load((const uint32_t*)&IncA[(size_t)pred * 64 + c],
                                       __ATOMIC_RELAXED, __HIP_MEMORY_SCOPE_AGENT));
            Pb = u2f(__hip_atomic_load((const uint32_t*)&IncB[(size_t)pred * 64 + c],
                                       __ATOMIC_RELAXED, __HIP_MEMORY_SCOPE_AGENT));
        }
        const float Ia = ea * Pa;
        const float Ib = ea * Pb + eb;
        __hip_atomic_store((uint32_t*)&IncA[(size_t)bi * 64 + c], f2u(Ia),
                           __ATOMIC_RELAXED, __HIP_MEMORY_SCOPE_AGENT);
        __hip_atomic_store((uint32_t*)&IncB[(size_t)bi * 64 + c], f2u(Ib),
                           __ATOMIC_RELAXED, __HIP_MEMORY_SCOPE_AGENT);
        __hip_atomic_store(&flags[bi], READY, __ATOMIC_RELEASE,
                           __HIP_MEMORY_SCOPE_AGENT);
        tPb[c] = Pb;
    }
    __syncthreads();

    // phase D: replay with carry, write silu(o1)*h (coalesced 128-B rows)
    uint4 oa[8];
#pragma unroll
    for (int j = 0; j < 8; ++j) oa[j] = *(const uint4*)(op + j * 8);
    const ushort_t* os = (const ushort_t*)oa;

    float h = tEa[tseg][ch_l] * tPb[ch_l] + tEb[tseg][ch_l];
    z1 = zw1; z2 = zw2; z3 = zw3;
    ushort_t* up = u + pos * (size_t)HID + ch;
#pragma unroll
    for (int t = 0; t < 64; ++t) {
        const float zr = bf2f(zs[t]);
        const float hr = bf2f(hs[t]);
        const float o1 = bf2f(os[t]);
        const float cv = w0 * z3 + w1 * z2 + w2 * z1 + w3 * zr;
        const float s  = sigm(cv);
        z3 = z2; z2 = z1; z1 = zr;
        h = (1.f - s) * h + s * hr;
        up[(size_t)t * HID] = f2bf(o1 * sigm(o1) * h);
    }
}

// ---------------------------------------------------------------------------
extern "C" void kernel_launch(void* const* d_in, const int* in_sizes, int n_in,
                              void* d_out, int out_size, void* d_ws, size_t ws_size,
                              hipStream_t stream) {
    const float* x  = (const float*)d_in[0];
    const float* w1 = (const float*)d_in[1];
    const float* w2 = (const float*)d_in[2];
    const float* cw = (const float*)d_in[3];
    char* ws = (char*)d_ws;

    // ws layout (bytes): xb 16MiB | w1b 12MiB | w2b 4MiB | yT 96MiB | u 32MiB
    ushort_t* xb  = (ushort_t*)(ws);
    ushort_t* w1b = (ushort_t*)(ws + (size_t)16777216);
    ushort_t* w2b = (ushort_t*)(ws + (size_t)29360128);
    ushort_t* yT  = (ushort_t*)(ws + (size_t)33554432);
    ushort_t* u   = (ushort_t*)(ws + (size_t)134217728);
    // look-back scratch reuses the w1b region (dead after GEMM1):
    float* IncA     = (float*)(ws + (size_t)16777216);            // 256 KiB
    float* IncB     = (float*)(ws + (size_t)16777216 + 262144);   // 256 KiB
    uint32_t* flags = (uint32_t*)(ws + (size_t)16777216 + 524288);// 4 KiB
    float* out = (float*)d_out;

    cvt_kernel<<<16384, 256, 0, stream>>>(x, w1, w2, xb, w1b, w2b);
    gemm_bt<1><<<dim3(N1 / 128, MROWS / 128), 256, 0, stream>>>(
        xb, w1b, (void*)yT, MROWS, N1, K1);
    hipMemsetAsync(flags, 0, 4096, stream);
    scan_lookback<<<1024, 256, 0, stream>>>(yT, cw, IncA, IncB, flags, u);
    gemm_bt<0><<<dim3(N2 / 128, MROWS / 128), 256, 0, stream>>>(
        u, w2b, (void*)out, MROWS, N2, K2);
}

// Round 6
// 355.881 us; speedup vs baseline: 1.9519x; 1.9519x over previous
//
#include <hip/hip_runtime.h>
#include <cstdint>

#define EMB 1024
#define HID 2048
#define BATCH 4
#define SEQ 2048
#define MROWS (BATCH * SEQ) /* 8192 */
#define N1 (3 * HID)        /* 6144 */
#define K1 EMB              /* 1024 */
#define N2 EMB              /* 1024 */
#define K2 HID              /* 2048 */

#define NX (MROWS * EMB)  /* 8388608 */
#define NW1 (N1 * K1)     /* 6291456 */
#define NW2 (N2 * K2)     /* 2097152 */

#define SEG 32            /* global time segments */
#define SLEN (SEQ / SEG)  /* 64 steps per segment */

typedef unsigned short ushort_t;
typedef __bf16 bf16x8 __attribute__((ext_vector_type(8)));
typedef float f32x4 __attribute__((ext_vector_type(4)));
typedef ushort_t us4 __attribute__((ext_vector_type(4)));

__device__ __forceinline__ ushort_t f2bf(float f) {
    uint32_t u = __builtin_bit_cast(uint32_t, f);
    u += 0x7fffu + ((u >> 16) & 1u);  // round-to-nearest-even
    return (ushort_t)(u >> 16);
}
__device__ __forceinline__ float bf2f(ushort_t h) {
    uint32_t u = ((uint32_t)h) << 16;
    return __builtin_bit_cast(float, u);
}
__device__ __forceinline__ float bflo(uint32_t v) {
    return __builtin_bit_cast(float, v << 16);
}
__device__ __forceinline__ float bfhi(uint32_t v) {
    return __builtin_bit_cast(float, v & 0xffff0000u);
}
__device__ __forceinline__ float sigm(float x) {
    return 1.f / (1.f + __expf(-x));
}

// async global->LDS, 16B per lane; LDS dest is wave-uniform base + lane*16
__device__ __forceinline__ void gload_lds16(const ushort_t* g, const ushort_t* l) {
    __builtin_amdgcn_global_load_lds(
        (const __attribute__((address_space(1))) void*)(uintptr_t)(g),
        (__attribute__((address_space(3))) void*)(uint32_t)(uintptr_t)(l),
        16, 0, 0);
}

// ---------------------------------------------------------------------------
// fp32 -> bf16 pre-convert of x, w1, w2
// ---------------------------------------------------------------------------
__global__ __launch_bounds__(256) void cvt_kernel(
    const float* __restrict__ x, const float* __restrict__ w1,
    const float* __restrict__ w2, ushort_t* __restrict__ xb,
    ushort_t* __restrict__ w1b, ushort_t* __restrict__ w2b) {
    const int i = (blockIdx.x * 256 + threadIdx.x) * 4;
    const float* s;
    ushort_t* d;
    if (i < NX) {
        s = x + i; d = xb + i;
    } else if (i < NX + NW1) {
        s = w1 + (i - NX); d = w1b + (i - NX);
    } else {
        s = w2 + (i - NX - NW1); d = w2b + (i - NX - NW1);
    }
    const float4 v = *(const float4*)s;
    us4 o;
    o.x = f2bf(v.x); o.y = f2bf(v.y); o.z = f2bf(v.z); o.w = f2bf(v.w);
    *(us4*)d = o;
}

// ---------------------------------------------------------------------------
// C[M,N] = A[M,K] * B[N,K]^T   (bf16 in, fp32 acc, bf16 or fp32 out)
// 128x128 tile, BK=32, 4 waves, each wave 64x64 via 4x4 mfma_f32_16x16x32_bf16
// N is the C row stride; the grid's x-extent may cover a column sub-range
// (caller offsets B and Cv). Bank-conflict-free swizzle (verified R2: 1.26e7->0).
// ---------------------------------------------------------------------------
template <bool OUT_BF16>
__global__ __launch_bounds__(256) void gemm_bt(
    const ushort_t* __restrict__ A, const ushort_t* __restrict__ B,
    void* __restrict__ Cv, int M, int N, int K) {
    __shared__ ushort_t sA[128 * 32];  // [m][kslot] row-major, 64B rows
    __shared__ ushort_t sB[128 * 32];  // [n][kslot] row-major

    const int tid  = threadIdx.x;
    const int lane = tid & 63;
    const int wave = tid >> 6;
    const int quad = lane >> 4;
    const int l16  = lane & 15;
    const long tm0 = (long)blockIdx.y * 128;
    const long tn0 = (long)blockIdx.x * 128;
    const int wm = (wave & 1) * 64;
    const int wn = (wave >> 1) * 64;

    f32x4 acc[4][4] = {};

    const int ar0 = tid >> 2;
    const int ar1 = (tid + 256) >> 2;
    const int kq  = (tid & 3) ^ ((ar0 >> 1) & 3);
    const int ac  = kq * 8;
    const ushort_t* gA = A + (size_t)tm0 * K;
    const ushort_t* gB = B + (size_t)tn0 * K;
    ushort_t* lb0 = &sA[0] + wave * 512;
    ushort_t* lb1 = &sA[0] + 2048 + wave * 512;
    ushort_t* lb2 = &sB[0] + wave * 512;
    ushort_t* lb3 = &sB[0] + 2048 + wave * 512;

    const int rsw = (l16 >> 1) & 3;
    const int aoff = (quad ^ rsw) * 8 + l16 * 32;

    for (int k0 = 0; k0 < K; k0 += 32) {
        __syncthreads();
        gload_lds16(gA + (size_t)ar0 * K + k0 + ac, lb0);
        gload_lds16(gA + (size_t)ar1 * K + k0 + ac, lb1);
        gload_lds16(gB + (size_t)ar0 * K + k0 + ac, lb2);
        gload_lds16(gB + (size_t)ar1 * K + k0 + ac, lb3);
        __syncthreads();

        bf16x8 af[4], bfr[4];
#pragma unroll
        for (int i = 0; i < 4; ++i)
            af[i] = *(const bf16x8*)&sA[(wm + i * 16) * 32 + aoff];
#pragma unroll
        for (int j = 0; j < 4; ++j)
            bfr[j] = *(const bf16x8*)&sB[(wn + j * 16) * 32 + aoff];
#pragma unroll
        for (int i = 0; i < 4; ++i)
#pragma unroll
            for (int j = 0; j < 4; ++j)
                acc[i][j] = __builtin_amdgcn_mfma_f32_16x16x32_bf16(
                    af[i], bfr[j], acc[i][j], 0, 0, 0);
    }

    // epilogue: C/D layout col=lane&15, row=quad*4+reg
#pragma unroll
    for (int i = 0; i < 4; ++i) {
        const long row0 = tm0 + wm + i * 16 + quad * 4;
#pragma unroll
        for (int j = 0; j < 4; ++j) {
            const long col = tn0 + wn + j * 16 + l16;
#pragma unroll
            for (int r = 0; r < 4; ++r) {
                if constexpr (OUT_BF16) {
                    ((ushort_t*)Cv)[(size_t)(row0 + r) * N + col] = f2bf(acc[i][j][r]);
                } else {
                    ((float*)Cv)[(size_t)(row0 + r) * N + col] = acc[i][j][r];
                }
            }
        }
    }
}

// ---------------------------------------------------------------------------
// Segmented scan, 3 kernels (R3 structure, validated). Thread owns 2 adjacent
// channels (ushort2 loads: 32 lanes x 4 B = full 128-B lines).
//   chslot = gid & 1023 (ch = 2*chslot), bs = gid>>10, b = bs>>5, seg = bs&31
// Scratch (fp32): Ag/Bg/Cr each [B][SEG][HID], 1 MiB apiece, carved from the
// xb region (dead after GEMM1 reads it).
// ---------------------------------------------------------------------------
__global__ __launch_bounds__(256) void scan_part1(
    const ushort_t* __restrict__ y, const float* __restrict__ cw,
    float* __restrict__ Ag, float* __restrict__ Bg) {
    const int gid = blockIdx.x * 256 + threadIdx.x;
    const int ch  = (gid & 1023) * 2;
    const int bs  = gid >> 10;
    const int b   = bs >> 5;
    const int seg = bs & 31;
    const int t0  = seg * SLEN;
    const size_t rowbase = (size_t)b * SEQ;
    const ushort_t* yz = y + 2048 + ch;
    const ushort_t* yh = y + 4096 + ch;

    float w[2][4];
#pragma unroll
    for (int c = 0; c < 2; ++c)
#pragma unroll
        for (int k = 0; k < 4; ++k) w[c][k] = cw[(ch + c) * 4 + k];

    auto ld2 = [&](const ushort_t* p, int t) -> uint32_t {
        return *(const uint32_t*)(p + (rowbase + (size_t)t) * 6144);
    };
    auto zpair = [&](int t, float* out) {
        if (t < 0) { out[0] = 0.f; out[1] = 0.f; }
        else { uint32_t v = ld2(yz, t); out[0] = bflo(v); out[1] = bfhi(v); }
    };

    float z1[2], z2[2], z3[2], A[2] = {1.f, 1.f}, Bv[2] = {0.f, 0.f};
    zpair(t0 - 1, z1); zpair(t0 - 2, z2); zpair(t0 - 3, z3);

#pragma unroll 4
    for (int t = t0; t < t0 + SLEN; ++t) {
        const uint32_t vz = ld2(yz, t);
        const uint32_t vh = ld2(yh, t);
        const float zr[2] = {bflo(vz), bfhi(vz)};
        const float hr[2] = {bflo(vh), bfhi(vh)};
#pragma unroll
        for (int c = 0; c < 2; ++c) {
            const float cv = w[c][0] * z3[c] + w[c][1] * z2[c] +
                             w[c][2] * z1[c] + w[c][3] * zr[c];
            const float s = sigm(cv);
            z3[c] = z2[c]; z2[c] = z1[c]; z1[c] = zr[c];
            const float a = 1.f - s;
            A[c] *= a;
            Bv[c] = a * Bv[c] + s * hr[c];
        }
    }
    const size_t idx = ((size_t)b * SEG + seg) * HID + ch;
    *(float2*)&Ag[idx] = make_float2(A[0], A[1]);
    *(float2*)&Bg[idx] = make_float2(Bv[0], Bv[1]);
}

// one thread per (b, ch): serial exclusive combine over SEG segments
__global__ __launch_bounds__(256) void scan_part2(
    const float* __restrict__ Ag, const float* __restrict__ Bg,
    float* __restrict__ Cr) {
    const int gid = blockIdx.x * 256 + threadIdx.x;  // [0, 8192)
    const int b  = gid >> 11;
    const int ch = gid & 2047;
    float carry = 0.f;
#pragma unroll
    for (int s = 0; s < SEG; ++s) {
        const size_t idx = ((size_t)b * SEG + s) * HID + ch;
        Cr[idx] = carry;
        carry = Ag[idx] * carry + Bg[idx];
    }
}

__global__ __launch_bounds__(256) void scan_part3(
    const ushort_t* __restrict__ y, const float* __restrict__ cw,
    const float* __restrict__ Cr, ushort_t* __restrict__ u) {
    const int gid = blockIdx.x * 256 + threadIdx.x;
    const int ch  = (gid & 1023) * 2;
    const int bs  = gid >> 10;
    const int b   = bs >> 5;
    const int seg = bs & 31;
    const int t0  = seg * SLEN;
    const size_t rowbase = (size_t)b * SEQ;
    const ushort_t* yo = y + ch;
    const ushort_t* yz = y + 2048 + ch;
    const ushort_t* yh = y + 4096 + ch;

    float w[2][4];
#pragma unroll
    for (int c = 0; c < 2; ++c)
#pragma unroll
        for (int k = 0; k < 4; ++k) w[c][k] = cw[(ch + c) * 4 + k];

    auto ld2 = [&](const ushort_t* p, int t) -> uint32_t {
        return *(const uint32_t*)(p + (rowbase + (size_t)t) * 6144);
    };
    auto zpair = [&](int t, float* out) {
        if (t < 0) { out[0] = 0.f; out[1] = 0.f; }
        else { uint32_t v = ld2(yz, t); out[0] = bflo(v); out[1] = bfhi(v); }
    };

    const size_t cidx = ((size_t)b * SEG + seg) * HID + ch;
    float h[2] = {Cr[cidx], Cr[cidx + 1]};
    float z1[2], z2[2], z3[2];
    zpair(t0 - 1, z1); zpair(t0 - 2, z2); zpair(t0 - 3, z3);

#pragma unroll 4
    for (int t = t0; t < t0 + SLEN; ++t) {
        const uint32_t vz = ld2(yz, t);
        const uint32_t vh = ld2(yh, t);
        const uint32_t vo = ld2(yo, t);
        const float zr[2] = {bflo(vz), bfhi(vz)};
        const float hr[2] = {bflo(vh), bfhi(vh)};
        const float o1[2] = {bflo(vo), bfhi(vo)};
        ushort_t res[2];
#pragma unroll
        for (int c = 0; c < 2; ++c) {
            const float cv = w[c][0] * z3[c] + w[c][1] * z2[c] +
                             w[c][2] * z1[c] + w[c][3] * zr[c];
            const float s = sigm(cv);
            z3[c] = z2[c]; z2[c] = z1[c]; z1[c] = zr[c];
            h[c] = (1.f - s) * h[c] + s * hr[c];
            const float sil = o1[c] * sigm(o1[c]);
            res[c] = f2bf(sil * h[c]);
        }
        *(uint32_t*)&u[(rowbase + (size_t)t) * (size_t)HID + ch] =
            (uint32_t)res[0] | ((uint32_t)res[1] << 16);
    }
}

// ---------------------------------------------------------------------------
extern "C" void kernel_launch(void* const* d_in, const int* in_sizes, int n_in,
                              void* d_out, int out_size, void* d_ws, size_t ws_size,
                              hipStream_t stream) {
    const float* x  = (const float*)d_in[0];
    const float* w1 = (const float*)d_in[1];
    const float* w2 = (const float*)d_in[2];
    const float* cw = (const float*)d_in[3];
    char* ws = (char*)d_ws;

    // ws layout (bytes): xb 16MiB | w1b 12MiB | w2b 4MiB | y 96MiB | u 32MiB = 160MiB
    ushort_t* xb  = (ushort_t*)(ws);
    ushort_t* w1b = (ushort_t*)(ws + (size_t)16777216);
    ushort_t* w2b = (ushort_t*)(ws + (size_t)29360128);
    ushort_t* y   = (ushort_t*)(ws + (size_t)33554432);
    ushort_t* u   = (ushort_t*)(ws + (size_t)134217728);
    // scan scratch reuses the xb region (dead after GEMM1): 3 x 1 MiB fp32
    float* Ag = (float*)(ws);
    float* Bg = (float*)(ws + (size_t)1048576);
    float* Cr = (float*)(ws + (size_t)2097152);
    float* out = (float*)d_out;

    cvt_kernel<<<16384, 256, 0, stream>>>(x, w1, w2, xb, w1b, w2b);
    // GEMM1 split into two column-half dispatches (diagnostic: each ~73 us so
    // every other dispatch surfaces in rocprof top-5). C stride stays N1.
    gemm_bt<true><<<dim3(N1 / 256, MROWS / 128), 256, 0, stream>>>(
        xb, w1b, (void*)y, MROWS, N1, K1);
    gemm_bt<true><<<dim3(N1 / 256, MROWS / 128), 256, 0, stream>>>(
        xb, w1b + (size_t)(N1 / 2) * K1, (void*)(y + N1 / 2), MROWS, N1, K1);
    scan_part1<<<512, 256, 0, stream>>>(y, cw, Ag, Bg);
    scan_part2<<<32, 256, 0, stream>>>(Ag, Bg, Cr);
    scan_part3<<<512, 256, 0, stream>>>(y, cw, Cr, u);
    gemm_bt<false><<<dim3(N2 / 128, MROWS / 128), 256, 0, stream>>>(
        u, w2b, (void*)out, MROWS, N2, K2);
}